// Round 4
// baseline (229.453 us; speedup 1.0000x reference)
//
#include <hip/hip_runtime.h>
#include <stdint.h>

typedef unsigned short u16;
typedef unsigned int   u32;

#define Bn 4
#define Cc 512
#define Hh 96
#define Ww 96
#define HWc (Hh*Ww)   // 9216
#define AH 11
#define Rr 512
#define CP (Cc/2)     // 256 dwords per point (bf16 NHWC)

__device__ __forceinline__ u16 f2bf(float f){
  u32 u = __float_as_uint(f);
  u += 0x7fffu + ((u>>16)&1u);
  return (u16)(u>>16);
}
__device__ __forceinline__ u32 pk2(float a, float b){
  return (u32)f2bf(a) | ((u32)f2bf(b)<<16);
}

// ---- fp32 NCHW -> bf16-pair (u32) NHWC transpose; 128hw x 128c tile ----
// LDS: u32 tile[128*64], XOR-swizzled col' = cp ^ (hw>>2)  -> conflict-free
__global__ __launch_bounds__(256)
void transpose_kernel(const float* __restrict__ in, u32* __restrict__ out){
  __shared__ u32 tile[128*64];   // 32 KB
  const int t = threadIdx.x;
  const int hw0 = blockIdx.x*128, c0 = blockIdx.y*128, b = blockIdx.z;
  {
    const int q = t & 31, cp0 = t >> 5;           // q: hw quad, cp0: 0..7
    const float* ib = in + ((size_t)(b*Cc + c0))*HWc + hw0 + 4*q;
    #pragma unroll
    for (int p=0;p<8;++p){
      const int cp = cp0 + p*8;                   // 0..63 channel pair in tile
      const float* pa = ib + (size_t)(2*cp)*HWc;
      float4 A = *(const float4*)pa;
      float4 B = *(const float4*)(pa + HWc);
      const int cs = cp ^ q;                      // (4q+i)>>2 == q for i<4
      tile[(4*q+0)*64 + cs] = pk2(A.x,B.x);
      tile[(4*q+1)*64 + cs] = pk2(A.y,B.y);
      tile[(4*q+2)*64 + cs] = pk2(A.z,B.z);
      tile[(4*q+3)*64 + cs] = pk2(A.w,B.w);
    }
  }
  __syncthreads();
  {
    const int l = t & 63, wv = t >> 6;            // lane = cp, wave = row group
    u32* ob = out + ((size_t)b*HWc + hw0)*CP + (c0>>1) + l;
    #pragma unroll
    for (int k=0;k<32;++k){
      const int hw = wv*32 + k;
      ob[(size_t)hw*CP] = tile[hw*64 + (l ^ (hw>>2))];  // 256B contiguous store
    }
  }
}

// per-bin bilinear combine, exact fp op order of the reference path
__device__ __forceinline__ float2 bilin(const u32 v[16], const float cw[4], const float rw[4]){
  float ax=0.0f, ay=0.0f;
  #pragma unroll
  for (int i=0;i<4;++i){
    float cx=0.0f, cy=0.0f;
    #pragma unroll
    for (int j=0;j<4;++j){
      u32 d = v[i*4+j];
      cx = fmaf(cw[j], __uint_as_float(d<<16),           cx);
      cy = fmaf(cw[j], __uint_as_float(d & 0xffff0000u), cy);
    }
    ax = fmaf(rw[i], cx, ax);
    ay = fmaf(rw[i], cy, ay);
  }
  return make_float2(ax, ay);
}

// ---- fused RoIAlignAda + 3x3/s2 maxpool, NHWC bf16 ----
// grid 2048, 128 threads (2 waves), fully independent blocks:
//   bid = rg*1024 + r*2 + half;  rg0: ph 0..6 -> oy{0,1,2}; rg1: ph 6..10 -> oy{3,4}
//   (row 6 recomputed by both: +9% loads, zero inter-block coupling)
//   rg0/rg1 of same (r,half) are 1024 apart -> same XCD under %8 round-robin.
// Inner loop processes TWO ph rows per pass: 32 loads in flight per pw step
// (2x per-wave MLP vs R0) while VGPR stays <=128 (col offsets/weights read
// per-pw from LDS, shared by the row pair, instead of 88-reg hoist).
__global__ __launch_bounds__(128)
void roi_align_max_nhwc(const u32* __restrict__ feat,
                        const float* __restrict__ rois,
                        float* __restrict__ out)
{
  __shared__ __align__(16) int4   s_ro[AH];      // row byte offsets (x4 dedup'd)
  __shared__ __align__(16) float4 s_rw[AH];
  __shared__ __align__(16) int4   s_co[AH];      // col byte offsets
  __shared__ __align__(16) float4 s_cw[AH];
  __shared__ int s_b;
  __shared__ __align__(16) float s_out[256*15];  // 15.36 KB (rg1 uses 10/15 slots)

  const int t    = threadIdx.x;
  const int bid  = blockIdx.x;
  const int rg   = bid >> 10;       // 0: rows 0..6, 1: rows 6..10
  const int rem  = bid & 1023;
  const int r    = rem >> 1;
  const int half = rem & 1;

  if (t == 0){
    int b = (int)rois[r*5+0];
    s_b = min(max(b, 0), Bn-1);
  }

  // geometry: threads 0..10 -> rows (ph), threads 64..74 -> cols (pw)
  if (t < AH || (t >= 64 && t < 64+AH)){
    const bool isrow = (t < AH);
    const int  p = isrow ? t : t-64;
    const float* rp = rois + r*5;
    const float c1 = rp[isrow?2:1], c2 = rp[isrow?4:3];
    // replicate np float32 ops exactly (no fp contraction at validity boundaries)
    float lo  = __fmul_rn(c1, 0.125f);
    float hi  = __fmul_rn(c2, 0.125f);
    float ext = fmaxf(__fsub_rn(hi,lo), 0.0f);
    float bin = __fdiv_rn(ext, 10.0f);
    float ctr = __fadd_rn(lo, __fmul_rn((float)p, bin));
    float strd = fmaxf(1.0f, rintf(__fdiv_rn(bin, 3.0f)));   // half-even == jnp.round
    bool ok = (ctr >= 0.0f) && (ctr < 96.0f);
    int rws[6]; float wts[6]; int nv=0;
    #pragma unroll
    for (int s=0;s<3;++s){
      float cc = __fadd_rn(ctr, __fmul_rn((float)(s-1), strd));
      bool vv = (cc >= 0.0f) && (cc < 96.0f);
      float fl = fminf(fmaxf(floorf(cc),0.0f),94.0f);
      float fr = __fsub_rn(cc, fl);
      int ri = (int)fl;
      rws[2*s]=ri; rws[2*s+1]=ri+1;
      wts[2*s]  = vv ? __fsub_rn(1.0f,fr) : 0.0f;
      wts[2*s+1]= vv ? fr : 0.0f;
      nv += vv?1:0;
    }
    float sc = ok ? (1.0f/(float)nv) : 0.0f;   // folds center_ok + 1/cnt (separable)
    // dedupe-merge (stride==1 here => <=4 unique), pad to 4 with w=0
    int cr[4]={0,0,0,0}; float cwv[4]={0.0f,0.0f,0.0f,0.0f}; int n=0;
    for (int k=0;k<6;++k){
      float wk=wts[k]; if (wk==0.0f) continue;
      int rr=rws[k]; bool fnd=false;
      for (int j=0;j<n;++j) if (cr[j]==rr){ cwv[j]+=wk; fnd=true; break; }
      if (!fnd && n<4){ cr[n]=rr; cwv[n]=wk; ++n; }
    }
    const int mul = isrow ? (Ww*CP*4) : (CP*4);   // BYTE offsets
    if (isrow){
      s_ro[p] = make_int4(cr[0]*mul, cr[1]*mul, cr[2]*mul, cr[3]*mul);
      s_rw[p] = make_float4(cwv[0]*sc, cwv[1]*sc, cwv[2]*sc, cwv[3]*sc);
    } else {
      s_co[p] = make_int4(cr[0]*mul, cr[1]*mul, cr[2]*mul, cr[3]*mul);
      s_cw[p] = make_float4(cwv[0]*sc, cwv[1]*sc, cwv[2]*sc, cwv[3]*sc);
    }
  }
  __syncthreads();

  const char* fb = (const char*)(feat + (size_t)s_b*((size_t)HWc*CP));
  const int tb4 = (half*128 + t)*4;            // byte offset of this thread's dword

  float2 awin[5];
  const int base  = rg ? 6 : 0;
  const int NFULL = rg ? 2 : 3;                // full row-pairs before the tail row

  #pragma unroll 1
  for (int pp=0; pp<NFULL; ++pp){
    const int pa = base + 2*pp;                // even row
    int4   ra4 = s_ro[pa];   float4 wa4 = s_rw[pa];
    int4   rb4 = s_ro[pa+1]; float4 wb4 = s_rw[pa+1];
    const char* ra0 = fb + __builtin_amdgcn_readfirstlane(ra4.x);
    const char* ra1 = fb + __builtin_amdgcn_readfirstlane(ra4.y);
    const char* ra2 = fb + __builtin_amdgcn_readfirstlane(ra4.z);
    const char* ra3 = fb + __builtin_amdgcn_readfirstlane(ra4.w);
    const char* rb0 = fb + __builtin_amdgcn_readfirstlane(rb4.x);
    const char* rb1 = fb + __builtin_amdgcn_readfirstlane(rb4.y);
    const char* rb2 = fb + __builtin_amdgcn_readfirstlane(rb4.z);
    const char* rb3 = fb + __builtin_amdgcn_readfirstlane(rb4.w);
    const float rwa[4] = {wa4.x, wa4.y, wa4.z, wa4.w};
    const float rwb[4] = {wb4.x, wb4.y, wb4.z, wb4.w};
    float2 bpp_a = make_float2(0.f,0.f), bp_a = bpp_a;
    float2 bpp_b = bpp_a, bp_b = bpp_a;
    #pragma unroll
    for (int pw=0; pw<AH; ++pw){
      int4 c4 = s_co[pw]; float4 w4 = s_cw[pw];
      const int oo[4] = {tb4 + c4.x, tb4 + c4.y, tb4 + c4.z, tb4 + c4.w};
      const float cwv[4] = {w4.x, w4.y, w4.z, w4.w};
      u32 va[16], vb[16];
      #pragma unroll
      for (int j=0;j<4;++j){
        va[0*4+j] = *(const u32*)(ra0 + oo[j]);
        va[1*4+j] = *(const u32*)(ra1 + oo[j]);
        va[2*4+j] = *(const u32*)(ra2 + oo[j]);
        va[3*4+j] = *(const u32*)(ra3 + oo[j]);
        vb[0*4+j] = *(const u32*)(rb0 + oo[j]);
        vb[1*4+j] = *(const u32*)(rb1 + oo[j]);
        vb[2*4+j] = *(const u32*)(rb2 + oo[j]);
        vb[3*4+j] = *(const u32*)(rb3 + oo[j]);
      }
      float2 ca = bilin(va, cwv, rwa);
      float2 cb = bilin(vb, cwv, rwb);
      if (pw >= 2 && !(pw & 1)){
        const int ox = (pw-2) >> 1;
        float2 rma, rmb;
        rma.x = fmaxf(fmaxf(bpp_a.x, bp_a.x), ca.x);
        rma.y = fmaxf(fmaxf(bpp_a.y, bp_a.y), ca.y);
        rmb.x = fmaxf(fmaxf(bpp_b.x, bp_b.x), cb.x);
        rmb.y = fmaxf(fmaxf(bpp_b.y, bp_b.y), cb.y);
        // FSM row a (even ph): first pair initializes, later pairs emit oy=pp-1
        if (pp == 0){
          awin[ox] = rma;
        } else {
          s_out[(2*t  )*15 + (pp-1)*5 + ox] = fmaxf(awin[ox].x, rma.x);
          s_out[(2*t+1)*15 + (pp-1)*5 + ox] = fmaxf(awin[ox].y, rma.y);
          awin[ox] = rma;
        }
        // FSM row b (odd ph): accumulate
        awin[ox].x = fmaxf(awin[ox].x, rmb.x);
        awin[ox].y = fmaxf(awin[ox].y, rmb.y);
      }
      bpp_a = bp_a; bp_a = ca;
      bpp_b = bp_b; bp_b = cb;
    }
  }

  // tail single row (ph = 6 for rg0, 10 for rg1): emits oy = NFULL-1 (local)
  {
    const int pa = base + 2*NFULL;
    int4   ra4 = s_ro[pa]; float4 wa4 = s_rw[pa];
    const char* ra0 = fb + __builtin_amdgcn_readfirstlane(ra4.x);
    const char* ra1 = fb + __builtin_amdgcn_readfirstlane(ra4.y);
    const char* ra2 = fb + __builtin_amdgcn_readfirstlane(ra4.z);
    const char* ra3 = fb + __builtin_amdgcn_readfirstlane(ra4.w);
    const float rwa[4] = {wa4.x, wa4.y, wa4.z, wa4.w};
    float2 bpp_a = make_float2(0.f,0.f), bp_a = bpp_a;
    #pragma unroll
    for (int pw=0; pw<AH; ++pw){
      int4 c4 = s_co[pw]; float4 w4 = s_cw[pw];
      const int oo[4] = {tb4 + c4.x, tb4 + c4.y, tb4 + c4.z, tb4 + c4.w};
      const float cwv[4] = {w4.x, w4.y, w4.z, w4.w};
      u32 va[16];
      #pragma unroll
      for (int j=0;j<4;++j){
        va[0*4+j] = *(const u32*)(ra0 + oo[j]);
        va[1*4+j] = *(const u32*)(ra1 + oo[j]);
        va[2*4+j] = *(const u32*)(ra2 + oo[j]);
        va[3*4+j] = *(const u32*)(ra3 + oo[j]);
      }
      float2 ca = bilin(va, cwv, rwa);
      if (pw >= 2 && !(pw & 1)){
        const int ox = (pw-2) >> 1;
        float2 rma;
        rma.x = fmaxf(fmaxf(bpp_a.x, bp_a.x), ca.x);
        rma.y = fmaxf(fmaxf(bpp_a.y, bp_a.y), ca.y);
        s_out[(2*t  )*15 + (NFULL-1)*5 + ox] = fmaxf(awin[ox].x, rma.x);
        s_out[(2*t+1)*15 + (NFULL-1)*5 + ox] = fmaxf(awin[ox].y, rma.y);
      }
      bpp_a = bp_a; bp_a = ca;
    }
  }
  __syncthreads();

  // store this block's slice: rg0 -> elems 0..14, rg1 -> elems 15..24 per channel
  float* ob = out + (size_t)r*(Cc*25) + half*(256*25);
  if (rg == 0){
    for (int k=t; k<256*15; k+=128){
      int c = k/15, e = k - c*15;
      ob[c*25 + e] = s_out[k];
    }
  } else {
    for (int k=t; k<256*10; k+=128){
      int c = k/10, e = k - c*10;
      ob[c*25 + 15 + e] = s_out[c*15 + e];
    }
  }
}

// ---- fallback: NCHW fp32 direct (known-correct, used only if ws too small) ----
__global__ __launch_bounds__(512, 1)
void roi_align_max_nchw(const float* __restrict__ feat,
                        const float* __restrict__ rois,
                        float* __restrict__ out)
{
  __shared__ int   s_roff[AH][6];
  __shared__ float s_rw  [AH][6];
  __shared__ int   s_coff[AH][6];
  __shared__ float s_cw  [AH][6];
  __shared__ int   s_b;
  __shared__ __align__(16) float s_out[Cc*25];

  const int t = threadIdx.x;
  const int r = blockIdx.x;

  if (t < AH*6){
    ((float*)s_rw)[t] = 0.0f;  ((int*)s_roff)[t] = 0;
    ((float*)s_cw)[t] = 0.0f;  ((int*)s_coff)[t] = 0;
  }
  if (t == 0){
    int b = (int)rois[r*5+0];
    s_b = min(max(b, 0), Bn-1);
  }
  __syncthreads();

  if (t < AH || (t >= 64 && t < 64+AH)){
    const bool isrow = (t < AH);
    const int  p = isrow ? t : t-64;
    const float* rp = rois + r*5;
    const float c1 = rp[isrow?2:1], c2 = rp[isrow?4:3];
    float lo  = __fmul_rn(c1, 0.125f);
    float hi  = __fmul_rn(c2, 0.125f);
    float ext = fmaxf(__fsub_rn(hi,lo), 0.0f);
    float bin = __fdiv_rn(ext, 10.0f);
    float ctr = __fadd_rn(lo, __fmul_rn((float)p, bin));
    float strd = fmaxf(1.0f, rintf(__fdiv_rn(bin, 3.0f)));
    bool ok = (ctr >= 0.0f) && (ctr < 96.0f);
    int rws[6]; float wts[6]; int nv=0;
    #pragma unroll
    for (int s=0;s<3;++s){
      float cc = __fadd_rn(ctr, __fmul_rn((float)(s-1), strd));
      bool vv = (cc >= 0.0f) && (cc < 96.0f);
      float fl = fminf(fmaxf(floorf(cc),0.0f),94.0f);
      float fr = __fsub_rn(cc, fl);
      int ri = (int)fl;
      rws[2*s]=ri; rws[2*s+1]=ri+1;
      wts[2*s]  = vv ? __fsub_rn(1.0f,fr) : 0.0f;
      wts[2*s+1]= vv ? fr : 0.0f;
      nv += vv?1:0;
    }
    float sc = ok ? (1.0f/(float)nv) : 0.0f;
    int cr[6]; float cw[6]; int n=0;
    for (int k=0;k<6;++k){
      float wk=wts[k]; if (wk==0.0f) continue;
      if (n>0 && cr[n-1]==rws[k]) cw[n-1]+=wk;
      else { cr[n]=rws[k]; cw[n]=wk; ++n; }
    }
    const int mul = isrow ? Ww : 1;
    for (int k=0;k<n;++k){
      int off = cr[k]*mul;
      float wv = cw[k]*sc;
      if (isrow){ s_roff[p][k]=off; s_rw[p][k]=wv; }
      else      { s_coff[p][k]=off; s_cw[p][k]=wv; }
    }
  }
  __syncthreads();

  const float* f0 = feat + ((size_t)s_b*Cc + t)*HWc;
  float awin[5];
  for (int ph=0; ph<AH; ++ph){
    float binrow[AH];
    #pragma unroll
    for (int pw=0; pw<AH; ++pw){
      float acc = 0.0f;
      #pragma unroll
      for (int ai=0; ai<6; ++ai){
        float ra = s_rw[ph][ai];
        if (ra == 0.0f) continue;
        int ro = s_roff[ph][ai];
        #pragma unroll
        for (int bi=0; bi<6; ++bi){
          float cb = s_cw[pw][bi];
          if (cb == 0.0f) continue;
          acc = fmaf(ra*cb, f0[ro + s_coff[pw][bi]], acc);
        }
      }
      binrow[pw] = acc;
    }
    float rm[5];
    #pragma unroll
    for (int ox=0; ox<5; ++ox)
      rm[ox] = fmaxf(fmaxf(binrow[2*ox], binrow[2*ox+1]), binrow[2*ox+2]);
    if (ph == 0){
      #pragma unroll
      for (int ox=0; ox<5; ++ox) awin[ox] = rm[ox];
    } else if (ph & 1){
      #pragma unroll
      for (int ox=0; ox<5; ++ox) awin[ox] = fmaxf(awin[ox], rm[ox]);
    } else {
      int oy = (ph-2) >> 1;
      #pragma unroll
      for (int ox=0; ox<5; ++ox){
        s_out[t*25 + oy*5 + ox] = fmaxf(awin[ox], rm[ox]);
        awin[ox] = rm[ox];
      }
    }
  }
  __syncthreads();

  float4* dst = (float4*)(out + (size_t)r*(Cc*25));
  const float4* src = (const float4*)s_out;
  for (int k=t; k<(Cc*25)/4; k+=512) dst[k]=src[k];
}

extern "C" void kernel_launch(void* const* d_in, const int* in_sizes, int n_in,
                              void* d_out, int out_size, void* d_ws, size_t ws_size,
                              hipStream_t stream)
{
  (void)in_sizes; (void)n_in; (void)out_size;
  const float* feat = (const float*)d_in[0];
  const float* rois = (const float*)d_in[1];
  float* out = (float*)d_out;
  const size_t need = (size_t)Bn*HWc*Cc*sizeof(u16);   // 37.75 MB bf16 NHWC
  if (ws_size >= need){
    u32* ws = (u32*)d_ws;
    dim3 g(HWc/128, Cc/128, Bn);
    transpose_kernel<<<g, 256, 0, stream>>>(feat, ws);
    roi_align_max_nhwc<<<Rr*4, 128, 0, stream>>>(ws, rois, out);
  } else {
    roi_align_max_nchw<<<Rr, 512, 0, stream>>>(feat, rois, out);
  }
}

// Round 5
// 167.878 us; speedup vs baseline: 1.3668x; 1.3668x over previous
//
#include <hip/hip_runtime.h>
#include <stdint.h>

typedef unsigned short u16;
typedef unsigned int   u32;

#define Bn 4
#define Cc 512
#define Hh 96
#define Ww 96
#define HWc (Hh*Ww)   // 9216
#define AH 11
#define Rr 512
#define CP (Cc/2)     // 256 dwords per point (bf16 NHWC)

__device__ __forceinline__ u16 f2bf(float f){
  u32 u = __float_as_uint(f);
  u += 0x7fffu + ((u>>16)&1u);
  return (u16)(u>>16);
}
__device__ __forceinline__ u32 pk2(float a, float b){
  return (u32)f2bf(a) | ((u32)f2bf(b)<<16);
}

// ---- fp32 NCHW -> bf16-pair (u32) NHWC transpose; 128hw x 128c tile ----
// LDS: u32 tile[128*64], XOR-swizzled col' = cp ^ (hw>>2)  -> conflict-free
__global__ __launch_bounds__(256)
void transpose_kernel(const float* __restrict__ in, u32* __restrict__ out){
  __shared__ u32 tile[128*64];   // 32 KB
  const int t = threadIdx.x;
  const int hw0 = blockIdx.x*128, c0 = blockIdx.y*128, b = blockIdx.z;
  {
    const int q = t & 31, cp0 = t >> 5;           // q: hw quad, cp0: 0..7
    const float* ib = in + ((size_t)(b*Cc + c0))*HWc + hw0 + 4*q;
    #pragma unroll
    for (int p=0;p<8;++p){
      const int cp = cp0 + p*8;                   // 0..63 channel pair in tile
      const float* pa = ib + (size_t)(2*cp)*HWc;
      float4 A = *(const float4*)pa;
      float4 B = *(const float4*)(pa + HWc);
      const int cs = cp ^ q;                      // (4q+i)>>2 == q for i<4
      tile[(4*q+0)*64 + cs] = pk2(A.x,B.x);
      tile[(4*q+1)*64 + cs] = pk2(A.y,B.y);
      tile[(4*q+2)*64 + cs] = pk2(A.z,B.z);
      tile[(4*q+3)*64 + cs] = pk2(A.w,B.w);
    }
  }
  __syncthreads();
  {
    const int l = t & 63, wv = t >> 6;            // lane = cp, wave = row group
    u32* ob = out + ((size_t)b*HWc + hw0)*CP + (c0>>1) + l;
    #pragma unroll
    for (int k=0;k<32;++k){
      const int hw = wv*32 + k;
      ob[(size_t)hw*CP] = tile[hw*64 + (l ^ (hw>>2))];  // 256B contiguous store
    }
  }
}

// per-bin bilinear combine, exact fp op order of the reference path
__device__ __forceinline__ float2 bilin(const u32 v[16], const float cw[4], const float rw[4]){
  float ax=0.0f, ay=0.0f;
  #pragma unroll
  for (int i=0;i<4;++i){
    float cx=0.0f, cy=0.0f;
    #pragma unroll
    for (int j=0;j<4;++j){
      u32 d = v[i*4+j];
      cx = fmaf(cw[j], __uint_as_float(d<<16),           cx);
      cy = fmaf(cw[j], __uint_as_float(d & 0xffff0000u), cy);
    }
    ax = fmaf(rw[i], cx, ax);
    ay = fmaf(rw[i], cy, ay);
  }
  return make_float2(ax, ay);
}

// ---- fused RoIAlignAda + 3x3/s2 maxpool, NHWC bf16, channel-split 2 ----
// grid 1024: r = bid>>1, half = bid&1; 128 threads; thread t owns dword half*128+t
// R5: R0 structure (best: 66us) + explicit 3-deep pw software pipeline:
//   bins pw+1..pw+3 prefetched into rotating named bufs va/vb/vc so the math
//   for bin pw runs with 32 gathers still in flight (vmcnt(32) not vmcnt(0)).
//   VGPR headroom is free: supply is 2 waves/SIMD (4 blk/CU x 2 waves).
__global__ __launch_bounds__(128)
void roi_align_max_nhwc(const u32* __restrict__ feat,
                        const float* __restrict__ rois,
                        float* __restrict__ out)
{
  __shared__ __align__(16) int4   s_ro[AH];
  __shared__ __align__(16) float4 s_rw[AH];
  __shared__ __align__(16) int4   s_co[AH];
  __shared__ __align__(16) float4 s_cw[AH];
  __shared__ int s_b;
  __shared__ __align__(16) float s_out[256*25];   // 25.6 KB

  const int t    = threadIdx.x;
  const int r    = blockIdx.x >> 1;
  const int half = blockIdx.x & 1;

  if (t == 0){
    int b = (int)rois[r*5+0];
    s_b = min(max(b, 0), Bn-1);
  }

  // geometry: threads 0..10 -> rows (ph), threads 64..74 -> cols (pw)
  if (t < AH || (t >= 64 && t < 64+AH)){
    const bool isrow = (t < AH);
    const int  p = isrow ? t : t-64;
    const float* rp = rois + r*5;
    const float c1 = rp[isrow?2:1], c2 = rp[isrow?4:3];
    // replicate np float32 ops exactly (no fp contraction at validity boundaries)
    float lo  = __fmul_rn(c1, 0.125f);
    float hi  = __fmul_rn(c2, 0.125f);
    float ext = fmaxf(__fsub_rn(hi,lo), 0.0f);
    float bin = __fdiv_rn(ext, 10.0f);
    float ctr = __fadd_rn(lo, __fmul_rn((float)p, bin));
    float strd = fmaxf(1.0f, rintf(__fdiv_rn(bin, 3.0f)));   // half-even == jnp.round
    bool ok = (ctr >= 0.0f) && (ctr < 96.0f);
    int rws[6]; float wts[6]; int nv=0;
    #pragma unroll
    for (int s=0;s<3;++s){
      float cc = __fadd_rn(ctr, __fmul_rn((float)(s-1), strd));
      bool vv = (cc >= 0.0f) && (cc < 96.0f);
      float fl = fminf(fmaxf(floorf(cc),0.0f),94.0f);
      float fr = __fsub_rn(cc, fl);
      int ri = (int)fl;
      rws[2*s]=ri; rws[2*s+1]=ri+1;
      wts[2*s]  = vv ? __fsub_rn(1.0f,fr) : 0.0f;
      wts[2*s+1]= vv ? fr : 0.0f;
      nv += vv?1:0;
    }
    float sc = ok ? (1.0f/(float)nv) : 0.0f;   // folds center_ok + 1/cnt (separable)
    // dedupe-merge (stride==1 always for this input range => <=4 unique)
    int cr[4]={0,0,0,0}; float cwv[4]={0.0f,0.0f,0.0f,0.0f}; int n=0;
    for (int k=0;k<6;++k){
      float wk=wts[k]; if (wk==0.0f) continue;
      int rr=rws[k]; bool fnd=false;
      for (int j=0;j<n;++j) if (cr[j]==rr){ cwv[j]+=wk; fnd=true; break; }
      if (!fnd && n<4){ cr[n]=rr; cwv[n]=wk; ++n; }
    }
    const int mul = isrow ? (Ww*CP*4) : (CP*4);   // BYTE offsets
    if (isrow){
      s_ro[p] = make_int4(cr[0]*mul, cr[1]*mul, cr[2]*mul, cr[3]*mul);
      s_rw[p] = make_float4(cwv[0]*sc, cwv[1]*sc, cwv[2]*sc, cwv[3]*sc);
    } else {
      s_co[p] = make_int4(cr[0]*mul, cr[1]*mul, cr[2]*mul, cr[3]*mul);
      s_cw[p] = make_float4(cwv[0]*sc, cwv[1]*sc, cwv[2]*sc, cwv[3]*sc);
    }
  }
  __syncthreads();

  const char* fb = (const char*)(feat + (size_t)s_b*((size_t)HWc*CP));
  const int tb4 = (half*128 + t)*4;            // byte offset of this thread's dword

  // hoist column byte-voffsets + weights into registers (R0-proven pattern)
  int   vo[AH][4]; float cwr[AH][4];
  #pragma unroll
  for (int pw=0; pw<AH; ++pw){
    int4 c4 = s_co[pw]; float4 w4 = s_cw[pw];
    vo[pw][0]=tb4+c4.x; vo[pw][1]=tb4+c4.y; vo[pw][2]=tb4+c4.z; vo[pw][3]=tb4+c4.w;
    cwr[pw][0]=w4.x; cwr[pw][1]=w4.y; cwr[pw][2]=w4.z; cwr[pw][3]=w4.w;
  }

  float2 awin[5];
  #pragma unroll 1
  for (int ph=0; ph<AH; ++ph){
    int4   r4 = s_ro[ph];
    float4 w4 = s_rw[ph];
    // scalar row bases (SGPR-pair addressing for the gathers)
    const char* r0 = fb + __builtin_amdgcn_readfirstlane(r4.x);
    const char* r1 = fb + __builtin_amdgcn_readfirstlane(r4.y);
    const char* r2 = fb + __builtin_amdgcn_readfirstlane(r4.z);
    const char* r3 = fb + __builtin_amdgcn_readfirstlane(r4.w);
    const float rw_[4] = {w4.x, w4.y, w4.z, w4.w};
    float2 binr[AH];
    u32 va[16], vb[16], vc[16];

#define LDV(dst, PW) do{                              \
    dst[ 0] = *(const u32*)(r0 + vo[PW][0]);          \
    dst[ 1] = *(const u32*)(r0 + vo[PW][1]);          \
    dst[ 2] = *(const u32*)(r0 + vo[PW][2]);          \
    dst[ 3] = *(const u32*)(r0 + vo[PW][3]);          \
    dst[ 4] = *(const u32*)(r1 + vo[PW][0]);          \
    dst[ 5] = *(const u32*)(r1 + vo[PW][1]);          \
    dst[ 6] = *(const u32*)(r1 + vo[PW][2]);          \
    dst[ 7] = *(const u32*)(r1 + vo[PW][3]);          \
    dst[ 8] = *(const u32*)(r2 + vo[PW][0]);          \
    dst[ 9] = *(const u32*)(r2 + vo[PW][1]);          \
    dst[10] = *(const u32*)(r2 + vo[PW][2]);          \
    dst[11] = *(const u32*)(r2 + vo[PW][3]);          \
    dst[12] = *(const u32*)(r3 + vo[PW][0]);          \
    dst[13] = *(const u32*)(r3 + vo[PW][1]);          \
    dst[14] = *(const u32*)(r3 + vo[PW][2]);          \
    dst[15] = *(const u32*)(r3 + vo[PW][3]);          \
  }while(0)
#define CMP(src, PW) binr[PW] = bilin(src, cwr[PW], rw_)

    // 3-deep pipeline: math for bin pw overlaps 32 in-flight gathers
    LDV(va, 0); LDV(vb, 1); LDV(vc, 2);
    CMP(va, 0); LDV(va, 3);
    CMP(vb, 1); LDV(vb, 4);
    CMP(vc, 2); LDV(vc, 5);
    CMP(va, 3); LDV(va, 6);
    CMP(vb, 4); LDV(vb, 7);
    CMP(vc, 5); LDV(vc, 8);
    CMP(va, 6); LDV(va, 9);
    CMP(vb, 7); LDV(vb, 10);
    CMP(vc, 8);
    CMP(va, 9);
    CMP(vb, 10);
#undef LDV
#undef CMP

    float2 rm[5];
    #pragma unroll
    for (int ox=0; ox<5; ++ox){
      rm[ox].x = fmaxf(fmaxf(binr[2*ox].x, binr[2*ox+1].x), binr[2*ox+2].x);
      rm[ox].y = fmaxf(fmaxf(binr[2*ox].y, binr[2*ox+1].y), binr[2*ox+2].y);
    }
    if (ph == 0){
      #pragma unroll
      for (int ox=0; ox<5; ++ox) awin[ox] = rm[ox];
    } else if (ph & 1){
      #pragma unroll
      for (int ox=0; ox<5; ++ox){
        awin[ox].x = fmaxf(awin[ox].x, rm[ox].x);
        awin[ox].y = fmaxf(awin[ox].y, rm[ox].y);
      }
    } else {
      const int oy = (ph-2) >> 1;
      #pragma unroll
      for (int ox=0; ox<5; ++ox){
        s_out[(2*t  )*25 + oy*5 + ox] = fmaxf(awin[ox].x, rm[ox].x);
        s_out[(2*t+1)*25 + oy*5 + ox] = fmaxf(awin[ox].y, rm[ox].y);
        awin[ox] = rm[ox];
      }
    }
  }
  __syncthreads();

  // coalesced float4 store of this half's [256][5][5] chunk
  float4* dst = (float4*)(out + (size_t)r*(Cc*25) + half*(256*25));
  const float4* src = (const float4*)s_out;
  for (int k=t; k<(256*25)/4; k+=128) dst[k]=src[k];
}

// ---- fallback: NCHW fp32 direct (known-correct, used only if ws too small) ----
__global__ __launch_bounds__(512, 1)
void roi_align_max_nchw(const float* __restrict__ feat,
                        const float* __restrict__ rois,
                        float* __restrict__ out)
{
  __shared__ int   s_roff[AH][6];
  __shared__ float s_rw  [AH][6];
  __shared__ int   s_coff[AH][6];
  __shared__ float s_cw  [AH][6];
  __shared__ int   s_b;
  __shared__ __align__(16) float s_out[Cc*25];

  const int t = threadIdx.x;
  const int r = blockIdx.x;

  if (t < AH*6){
    ((float*)s_rw)[t] = 0.0f;  ((int*)s_roff)[t] = 0;
    ((float*)s_cw)[t] = 0.0f;  ((int*)s_coff)[t] = 0;
  }
  if (t == 0){
    int b = (int)rois[r*5+0];
    s_b = min(max(b, 0), Bn-1);
  }
  __syncthreads();

  if (t < AH || (t >= 64 && t < 64+AH)){
    const bool isrow = (t < AH);
    const int  p = isrow ? t : t-64;
    const float* rp = rois + r*5;
    const float c1 = rp[isrow?2:1], c2 = rp[isrow?4:3];
    float lo  = __fmul_rn(c1, 0.125f);
    float hi  = __fmul_rn(c2, 0.125f);
    float ext = fmaxf(__fsub_rn(hi,lo), 0.0f);
    float bin = __fdiv_rn(ext, 10.0f);
    float ctr = __fadd_rn(lo, __fmul_rn((float)p, bin));
    float strd = fmaxf(1.0f, rintf(__fdiv_rn(bin, 3.0f)));
    bool ok = (ctr >= 0.0f) && (ctr < 96.0f);
    int rws[6]; float wts[6]; int nv=0;
    #pragma unroll
    for (int s=0;s<3;++s){
      float cc = __fadd_rn(ctr, __fmul_rn((float)(s-1), strd));
      bool vv = (cc >= 0.0f) && (cc < 96.0f);
      float fl = fminf(fmaxf(floorf(cc),0.0f),94.0f);
      float fr = __fsub_rn(cc, fl);
      int ri = (int)fl;
      rws[2*s]=ri; rws[2*s+1]=ri+1;
      wts[2*s]  = vv ? __fsub_rn(1.0f,fr) : 0.0f;
      wts[2*s+1]= vv ? fr : 0.0f;
      nv += vv?1:0;
    }
    float sc = ok ? (1.0f/(float)nv) : 0.0f;
    int cr[6]; float cw[6]; int n=0;
    for (int k=0;k<6;++k){
      float wk=wts[k]; if (wk==0.0f) continue;
      if (n>0 && cr[n-1]==rws[k]) cw[n-1]+=wk;
      else { cr[n]=rws[k]; cw[n]=wk; ++n; }
    }
    const int mul = isrow ? Ww : 1;
    for (int k=0;k<n;++k){
      int off = cr[k]*mul;
      float wv = cw[k]*sc;
      if (isrow){ s_roff[p][k]=off; s_rw[p][k]=wv; }
      else      { s_coff[p][k]=off; s_cw[p][k]=wv; }
    }
  }
  __syncthreads();

  const float* f0 = feat + ((size_t)s_b*Cc + t)*HWc;
  float awin[5];
  for (int ph=0; ph<AH; ++ph){
    float binrow[AH];
    #pragma unroll
    for (int pw=0; pw<AH; ++pw){
      float acc = 0.0f;
      #pragma unroll
      for (int ai=0; ai<6; ++ai){
        float ra = s_rw[ph][ai];
        if (ra == 0.0f) continue;
        int ro = s_roff[ph][ai];
        #pragma unroll
        for (int bi=0; bi<6; ++bi){
          float cb = s_cw[pw][bi];
          if (cb == 0.0f) continue;
          acc = fmaf(ra*cb, f0[ro + s_coff[pw][bi]], acc);
        }
      }
      binrow[pw] = acc;
    }
    float rm[5];
    #pragma unroll
    for (int ox=0; ox<5; ++ox)
      rm[ox] = fmaxf(fmaxf(binrow[2*ox], binrow[2*ox+1]), binrow[2*ox+2]);
    if (ph == 0){
      #pragma unroll
      for (int ox=0; ox<5; ++ox) awin[ox] = rm[ox];
    } else if (ph & 1){
      #pragma unroll
      for (int ox=0; ox<5; ++ox) awin[ox] = fmaxf(awin[ox], rm[ox]);
    } else {
      int oy = (ph-2) >> 1;
      #pragma unroll
      for (int ox=0; ox<5; ++ox){
        s_out[t*25 + oy*5 + ox] = fmaxf(awin[ox], rm[ox]);
        awin[ox] = rm[ox];
      }
    }
  }
  __syncthreads();

  float4* dst = (float4*)(out + (size_t)r*(Cc*25));
  const float4* src = (const float4*)s_out;
  for (int k=t; k<(Cc*25)/4; k+=512) dst[k]=src[k];
}

extern "C" void kernel_launch(void* const* d_in, const int* in_sizes, int n_in,
                              void* d_out, int out_size, void* d_ws, size_t ws_size,
                              hipStream_t stream)
{
  (void)in_sizes; (void)n_in; (void)out_size;
  const float* feat = (const float*)d_in[0];
  const float* rois = (const float*)d_in[1];
  float* out = (float*)d_out;
  const size_t need = (size_t)Bn*HWc*Cc*sizeof(u16);   // 37.75 MB bf16 NHWC
  if (ws_size >= need){
    u32* ws = (u32*)d_ws;
    dim3 g(HWc/128, Cc/128, Bn);
    transpose_kernel<<<g, 256, 0, stream>>>(feat, ws);
    roi_align_max_nhwc<<<Rr*2, 128, 0, stream>>>(ws, rois, out);
  } else {
    roi_align_max_nchw<<<Rr, 512, 0, stream>>>(feat, rois, out);
  }
}

// Round 6
// 164.049 us; speedup vs baseline: 1.3987x; 1.0233x over previous
//
#include <hip/hip_runtime.h>
#include <stdint.h>

typedef unsigned short u16;
typedef unsigned int   u32;

#define Bn 4
#define Cc 512
#define Hh 96
#define Ww 96
#define HWc (Hh*Ww)   // 9216
#define AH 11
#define Rr 512
#define CP (Cc/2)     // 256 dwords per point (bf16 NHWC)

__device__ __forceinline__ u16 f2bf(float f){
  u32 u = __float_as_uint(f);
  u += 0x7fffu + ((u>>16)&1u);
  return (u16)(u>>16);
}
__device__ __forceinline__ u32 pk2(float a, float b){
  return (u32)f2bf(a) | ((u32)f2bf(b)<<16);
}

// ---- fp32 NCHW -> bf16-pair (u32) NHWC transpose; 128hw x 128c tile ----
__global__ __launch_bounds__(256)
void transpose_kernel(const float* __restrict__ in, u32* __restrict__ out){
  __shared__ u32 tile[128*64];   // 32 KB
  const int t = threadIdx.x;
  const int hw0 = blockIdx.x*128, c0 = blockIdx.y*128, b = blockIdx.z;
  {
    const int q = t & 31, cp0 = t >> 5;           // q: hw quad, cp0: 0..7
    const float* ib = in + ((size_t)(b*Cc + c0))*HWc + hw0 + 4*q;
    #pragma unroll
    for (int p=0;p<8;++p){
      const int cp = cp0 + p*8;                   // 0..63 channel pair in tile
      const float* pa = ib + (size_t)(2*cp)*HWc;
      float4 A = *(const float4*)pa;
      float4 B = *(const float4*)(pa + HWc);
      const int cs = cp ^ q;                      // (4q+i)>>2 == q for i<4
      tile[(4*q+0)*64 + cs] = pk2(A.x,B.x);
      tile[(4*q+1)*64 + cs] = pk2(A.y,B.y);
      tile[(4*q+2)*64 + cs] = pk2(A.z,B.z);
      tile[(4*q+3)*64 + cs] = pk2(A.w,B.w);
    }
  }
  __syncthreads();
  {
    const int l = t & 63, wv = t >> 6;            // lane = cp, wave = row group
    u32* ob = out + ((size_t)b*HWc + hw0)*CP + (c0>>1) + l;
    #pragma unroll
    for (int k=0;k<32;++k){
      const int hw = wv*32 + k;
      ob[(size_t)hw*CP] = tile[hw*64 + (l ^ (hw>>2))];  // 256B contiguous store
    }
  }
}

// ---- tiny counting-sort of roi indices by batch: idx[0..3]=cnt, [4..7]=off,
// [8..8+512)=roi ids grouped by batch ----
__global__ __launch_bounds__(512)
void roi_sort(const float* __restrict__ rois, int* __restrict__ idx){
  __shared__ int cnt[4], off[4], cur[4];
  const int t = threadIdx.x;
  int b = min(max((int)rois[t*5], 0), Bn-1);
  if (t < 4){ cnt[t] = 0; }
  __syncthreads();
  atomicAdd(&cnt[b], 1);
  __syncthreads();
  if (t == 0){
    int o = 0;
    for (int i=0;i<4;++i){ off[i]=o; cur[i]=o; o+=cnt[i]; }
  }
  __syncthreads();
  int pos = atomicAdd(&cur[b], 1);
  idx[8+pos] = t;
  if (t < 4){ idx[t] = cnt[t]; idx[4+t] = off[t]; }
}

// per-bin bilinear combine, exact fp op order of the reference path
__device__ __forceinline__ float2 bilin(const u32 v[16], const float cw[4], const float rw[4]){
  float ax=0.0f, ay=0.0f;
  #pragma unroll
  for (int i=0;i<4;++i){
    float cx=0.0f, cy=0.0f;
    #pragma unroll
    for (int j=0;j<4;++j){
      u32 d = v[i*4+j];
      cx = fmaf(cw[j], __uint_as_float(d<<16),           cx);
      cy = fmaf(cw[j], __uint_as_float(d & 0xffff0000u), cy);
    }
    ax = fmaf(rw[i], cx, ax);
    ay = fmaf(rw[i], cy, ay);
  }
  return make_float2(ax, ay);
}

// ---- fused RoIAlignAda + 3x3/s2 maxpool, NHWC bf16, channel-split 2 ----
// R6 = R5 body (3-deep pw pipeline, 60.4us) + XCD-pinned roi->block mapping:
//   bid = 8j + k, k = XCD (round-robin %8). XCD k handles batch k>>1,
//   channel-half k&1. One (image, half) = 4.7 MB ~= one XCD L2 -> the ~3x
//   spatial roi overlap becomes L2 hits instead of L3 round-trips.
//   Leftover rois (batch counts != 128) fill deficit slots via bijective rank.
__global__ __launch_bounds__(128)
void roi_align_max_nhwc(const u32* __restrict__ feat,
                        const float* __restrict__ rois,
                        float* __restrict__ out,
                        const int* __restrict__ idx)
{
  __shared__ __align__(16) int4   s_ro[AH];
  __shared__ __align__(16) float4 s_rw[AH];
  __shared__ __align__(16) int4   s_co[AH];
  __shared__ __align__(16) float4 s_cw[AH];
  __shared__ int s_b;
  __shared__ __align__(16) float s_out[256*25];   // 25.6 KB

  const int t   = threadIdx.x;
  const int bid = blockIdx.x;

  int r, half;
  if (idx){
    const int k = bid & 7;          // XCD under %8 round-robin
    const int j = bid >> 3;         // 0..127 slot within XCD
    const int b = k >> 1;
    half = k & 1;
    const int cntb = idx[b];
    if (j < cntb && j < 128){
      r = idx[8 + idx[4+b] + j];    // native: j-th roi of this XCD's batch
    } else {
      // deficit slot: pull from the global leftover pool (bijective rank)
      int dr = 0;
      for (int b2=0; b2<b; ++b2) dr += max(0, 128 - idx[b2]);
      dr += j - min(cntb, 128);
      int acc = 0; r = 0;
      for (int b2=0; b2<4; ++b2){
        int ex = max(0, idx[b2] - 128);
        if (dr < acc + ex){ r = idx[8 + idx[4+b2] + 128 + (dr - acc)]; break; }
        acc += ex;
      }
    }
  } else {
    r = bid >> 1; half = bid & 1;
  }

  if (t == 0){
    int b = (int)rois[r*5+0];
    s_b = min(max(b, 0), Bn-1);
  }

  // geometry: threads 0..10 -> rows (ph), threads 64..74 -> cols (pw)
  if (t < AH || (t >= 64 && t < 64+AH)){
    const bool isrow = (t < AH);
    const int  p = isrow ? t : t-64;
    const float* rp = rois + r*5;
    const float c1 = rp[isrow?2:1], c2 = rp[isrow?4:3];
    // replicate np float32 ops exactly (no fp contraction at validity boundaries)
    float lo  = __fmul_rn(c1, 0.125f);
    float hi  = __fmul_rn(c2, 0.125f);
    float ext = fmaxf(__fsub_rn(hi,lo), 0.0f);
    float bin = __fdiv_rn(ext, 10.0f);
    float ctr = __fadd_rn(lo, __fmul_rn((float)p, bin));
    float strd = fmaxf(1.0f, rintf(__fdiv_rn(bin, 3.0f)));   // half-even == jnp.round
    bool ok = (ctr >= 0.0f) && (ctr < 96.0f);
    int rws[6]; float wts[6]; int nv=0;
    #pragma unroll
    for (int s=0;s<3;++s){
      float cc = __fadd_rn(ctr, __fmul_rn((float)(s-1), strd));
      bool vv = (cc >= 0.0f) && (cc < 96.0f);
      float fl = fminf(fmaxf(floorf(cc),0.0f),94.0f);
      float fr = __fsub_rn(cc, fl);
      int ri = (int)fl;
      rws[2*s]=ri; rws[2*s+1]=ri+1;
      wts[2*s]  = vv ? __fsub_rn(1.0f,fr) : 0.0f;
      wts[2*s+1]= vv ? fr : 0.0f;
      nv += vv?1:0;
    }
    float sc = ok ? (1.0f/(float)nv) : 0.0f;   // folds center_ok + 1/cnt (separable)
    // dedupe-merge (stride==1 here => <=4 unique), pad to 4 with w=0
    int cr[4]={0,0,0,0}; float cwv[4]={0.0f,0.0f,0.0f,0.0f}; int n=0;
    for (int k=0;k<6;++k){
      float wk=wts[k]; if (wk==0.0f) continue;
      int rr=rws[k]; bool fnd=false;
      for (int j=0;j<n;++j) if (cr[j]==rr){ cwv[j]+=wk; fnd=true; break; }
      if (!fnd && n<4){ cr[n]=rr; cwv[n]=wk; ++n; }
    }
    const int mul = isrow ? (Ww*CP*4) : (CP*4);   // BYTE offsets
    if (isrow){
      s_ro[p] = make_int4(cr[0]*mul, cr[1]*mul, cr[2]*mul, cr[3]*mul);
      s_rw[p] = make_float4(cwv[0]*sc, cwv[1]*sc, cwv[2]*sc, cwv[3]*sc);
    } else {
      s_co[p] = make_int4(cr[0]*mul, cr[1]*mul, cr[2]*mul, cr[3]*mul);
      s_cw[p] = make_float4(cwv[0]*sc, cwv[1]*sc, cwv[2]*sc, cwv[3]*sc);
    }
  }
  __syncthreads();

  const char* fb = (const char*)(feat + (size_t)s_b*((size_t)HWc*CP));
  const int tb4 = (half*128 + t)*4;            // byte offset of this thread's dword

  // hoist column byte-voffsets + weights into registers (R0-proven pattern)
  int   vo[AH][4]; float cwr[AH][4];
  #pragma unroll
  for (int pw=0; pw<AH; ++pw){
    int4 c4 = s_co[pw]; float4 w4 = s_cw[pw];
    vo[pw][0]=tb4+c4.x; vo[pw][1]=tb4+c4.y; vo[pw][2]=tb4+c4.z; vo[pw][3]=tb4+c4.w;
    cwr[pw][0]=w4.x; cwr[pw][1]=w4.y; cwr[pw][2]=w4.z; cwr[pw][3]=w4.w;
  }

  float2 awin[5];
  #pragma unroll 1
  for (int ph=0; ph<AH; ++ph){
    int4   r4 = s_ro[ph];
    float4 w4 = s_rw[ph];
    // scalar row bases (SGPR-pair addressing for the gathers)
    const char* r0 = fb + __builtin_amdgcn_readfirstlane(r4.x);
    const char* r1 = fb + __builtin_amdgcn_readfirstlane(r4.y);
    const char* r2 = fb + __builtin_amdgcn_readfirstlane(r4.z);
    const char* r3 = fb + __builtin_amdgcn_readfirstlane(r4.w);
    const float rw_[4] = {w4.x, w4.y, w4.z, w4.w};
    float2 binr[AH];
    u32 va[16], vb[16], vc[16];

#define LDV(dst, PW) do{                              \
    dst[ 0] = *(const u32*)(r0 + vo[PW][0]);          \
    dst[ 1] = *(const u32*)(r0 + vo[PW][1]);          \
    dst[ 2] = *(const u32*)(r0 + vo[PW][2]);          \
    dst[ 3] = *(const u32*)(r0 + vo[PW][3]);          \
    dst[ 4] = *(const u32*)(r1 + vo[PW][0]);          \
    dst[ 5] = *(const u32*)(r1 + vo[PW][1]);          \
    dst[ 6] = *(const u32*)(r1 + vo[PW][2]);          \
    dst[ 7] = *(const u32*)(r1 + vo[PW][3]);          \
    dst[ 8] = *(const u32*)(r2 + vo[PW][0]);          \
    dst[ 9] = *(const u32*)(r2 + vo[PW][1]);          \
    dst[10] = *(const u32*)(r2 + vo[PW][2]);          \
    dst[11] = *(const u32*)(r2 + vo[PW][3]);          \
    dst[12] = *(const u32*)(r3 + vo[PW][0]);          \
    dst[13] = *(const u32*)(r3 + vo[PW][1]);          \
    dst[14] = *(const u32*)(r3 + vo[PW][2]);          \
    dst[15] = *(const u32*)(r3 + vo[PW][3]);          \
  }while(0)
#define CMP(src, PW) binr[PW] = bilin(src, cwr[PW], rw_)

    // 3-deep pipeline: math for bin pw overlaps 32 in-flight gathers
    LDV(va, 0); LDV(vb, 1); LDV(vc, 2);
    CMP(va, 0); LDV(va, 3);
    CMP(vb, 1); LDV(vb, 4);
    CMP(vc, 2); LDV(vc, 5);
    CMP(va, 3); LDV(va, 6);
    CMP(vb, 4); LDV(vb, 7);
    CMP(vc, 5); LDV(vc, 8);
    CMP(va, 6); LDV(va, 9);
    CMP(vb, 7); LDV(vb, 10);
    CMP(vc, 8);
    CMP(va, 9);
    CMP(vb, 10);
#undef LDV
#undef CMP

    float2 rm[5];
    #pragma unroll
    for (int ox=0; ox<5; ++ox){
      rm[ox].x = fmaxf(fmaxf(binr[2*ox].x, binr[2*ox+1].x), binr[2*ox+2].x);
      rm[ox].y = fmaxf(fmaxf(binr[2*ox].y, binr[2*ox+1].y), binr[2*ox+2].y);
    }
    if (ph == 0){
      #pragma unroll
      for (int ox=0; ox<5; ++ox) awin[ox] = rm[ox];
    } else if (ph & 1){
      #pragma unroll
      for (int ox=0; ox<5; ++ox){
        awin[ox].x = fmaxf(awin[ox].x, rm[ox].x);
        awin[ox].y = fmaxf(awin[ox].y, rm[ox].y);
      }
    } else {
      const int oy = (ph-2) >> 1;
      #pragma unroll
      for (int ox=0; ox<5; ++ox){
        s_out[(2*t  )*25 + oy*5 + ox] = fmaxf(awin[ox].x, rm[ox].x);
        s_out[(2*t+1)*25 + oy*5 + ox] = fmaxf(awin[ox].y, rm[ox].y);
        awin[ox] = rm[ox];
      }
    }
  }
  __syncthreads();

  // coalesced float4 store of this half's [256][5][5] chunk
  float4* dst = (float4*)(out + (size_t)r*(Cc*25) + half*(256*25));
  const float4* src = (const float4*)s_out;
  for (int k=t; k<(256*25)/4; k+=128) dst[k]=src[k];
}

// ---- fallback: NCHW fp32 direct (known-correct, used only if ws too small) ----
__global__ __launch_bounds__(512, 1)
void roi_align_max_nchw(const float* __restrict__ feat,
                        const float* __restrict__ rois,
                        float* __restrict__ out)
{
  __shared__ int   s_roff[AH][6];
  __shared__ float s_rw  [AH][6];
  __shared__ int   s_coff[AH][6];
  __shared__ float s_cw  [AH][6];
  __shared__ int   s_b;
  __shared__ __align__(16) float s_out[Cc*25];

  const int t = threadIdx.x;
  const int r = blockIdx.x;

  if (t < AH*6){
    ((float*)s_rw)[t] = 0.0f;  ((int*)s_roff)[t] = 0;
    ((float*)s_cw)[t] = 0.0f;  ((int*)s_coff)[t] = 0;
  }
  if (t == 0){
    int b = (int)rois[r*5+0];
    s_b = min(max(b, 0), Bn-1);
  }
  __syncthreads();

  if (t < AH || (t >= 64 && t < 64+AH)){
    const bool isrow = (t < AH);
    const int  p = isrow ? t : t-64;
    const float* rp = rois + r*5;
    const float c1 = rp[isrow?2:1], c2 = rp[isrow?4:3];
    float lo  = __fmul_rn(c1, 0.125f);
    float hi  = __fmul_rn(c2, 0.125f);
    float ext = fmaxf(__fsub_rn(hi,lo), 0.0f);
    float bin = __fdiv_rn(ext, 10.0f);
    float ctr = __fadd_rn(lo, __fmul_rn((float)p, bin));
    float strd = fmaxf(1.0f, rintf(__fdiv_rn(bin, 3.0f)));
    bool ok = (ctr >= 0.0f) && (ctr < 96.0f);
    int rws[6]; float wts[6]; int nv=0;
    #pragma unroll
    for (int s=0;s<3;++s){
      float cc = __fadd_rn(ctr, __fmul_rn((float)(s-1), strd));
      bool vv = (cc >= 0.0f) && (cc < 96.0f);
      float fl = fminf(fmaxf(floorf(cc),0.0f),94.0f);
      float fr = __fsub_rn(cc, fl);
      int ri = (int)fl;
      rws[2*s]=ri; rws[2*s+1]=ri+1;
      wts[2*s]  = vv ? __fsub_rn(1.0f,fr) : 0.0f;
      wts[2*s+1]= vv ? fr : 0.0f;
      nv += vv?1:0;
    }
    float sc = ok ? (1.0f/(float)nv) : 0.0f;
    int cr[6]; float cw[6]; int n=0;
    for (int k=0;k<6;++k){
      float wk=wts[k]; if (wk==0.0f) continue;
      if (n>0 && cr[n-1]==rws[k]) cw[n-1]+=wk;
      else { cr[n]=rws[k]; cw[n]=wk; ++n; }
    }
    const int mul = isrow ? Ww : 1;
    for (int k=0;k<n;++k){
      int off = cr[k]*mul;
      float wv = cw[k]*sc;
      if (isrow){ s_roff[p][k]=off; s_rw[p][k]=wv; }
      else      { s_coff[p][k]=off; s_cw[p][k]=wv; }
    }
  }
  __syncthreads();

  const float* f0 = feat + ((size_t)s_b*Cc + t)*HWc;
  float awin[5];
  for (int ph=0; ph<AH; ++ph){
    float binrow[AH];
    #pragma unroll
    for (int pw=0; pw<AH; ++pw){
      float acc = 0.0f;
      #pragma unroll
      for (int ai=0; ai<6; ++ai){
        float ra = s_rw[ph][ai];
        if (ra == 0.0f) continue;
        int ro = s_roff[ph][ai];
        #pragma unroll
        for (int bi=0; bi<6; ++bi){
          float cb = s_cw[pw][bi];
          if (cb == 0.0f) continue;
          acc = fmaf(ra*cb, f0[ro + s_coff[pw][bi]], acc);
        }
      }
      binrow[pw] = acc;
    }
    float rm[5];
    #pragma unroll
    for (int ox=0; ox<5; ++ox)
      rm[ox] = fmaxf(fmaxf(binrow[2*ox], binrow[2*ox+1]), binrow[2*ox+2]);
    if (ph == 0){
      #pragma unroll
      for (int ox=0; ox<5; ++ox) awin[ox] = rm[ox];
    } else if (ph & 1){
      #pragma unroll
      for (int ox=0; ox<5; ++ox) awin[ox] = fmaxf(awin[ox], rm[ox]);
    } else {
      int oy = (ph-2) >> 1;
      #pragma unroll
      for (int ox=0; ox<5; ++ox){
        s_out[t*25 + oy*5 + ox] = fmaxf(awin[ox], rm[ox]);
        awin[ox] = rm[ox];
      }
    }
  }
  __syncthreads();

  float4* dst = (float4*)(out + (size_t)r*(Cc*25));
  const float4* src = (const float4*)s_out;
  for (int k=t; k<(Cc*25)/4; k+=512) dst[k]=src[k];
}

extern "C" void kernel_launch(void* const* d_in, const int* in_sizes, int n_in,
                              void* d_out, int out_size, void* d_ws, size_t ws_size,
                              hipStream_t stream)
{
  (void)in_sizes; (void)n_in; (void)out_size;
  const float* feat = (const float*)d_in[0];
  const float* rois = (const float*)d_in[1];
  float* out = (float*)d_out;
  const size_t need = (size_t)Bn*HWc*Cc*sizeof(u16);   // 37.75 MB bf16 NHWC
  if (ws_size >= need){
    u32* ws = (u32*)d_ws;
    int* idx = nullptr;
    if (ws_size >= need + 4096){
      idx = (int*)((char*)d_ws + need);
      roi_sort<<<1, 512, 0, stream>>>(rois, idx);
    }
    dim3 g(HWc/128, Cc/128, Bn);
    transpose_kernel<<<g, 256, 0, stream>>>(feat, ws);
    roi_align_max_nhwc<<<Rr*2, 128, 0, stream>>>(ws, rois, out, idx);
  } else {
    roi_align_max_nchw<<<Rr, 512, 0, stream>>>(feat, rois, out);
  }
}

// Round 7
// 161.904 us; speedup vs baseline: 1.4172x; 1.0132x over previous
//
#include <hip/hip_runtime.h>
#include <stdint.h>

typedef unsigned short u16;
typedef unsigned int   u32;

#define Bn 4
#define Cc 512
#define Hh 96
#define Ww 96
#define HWc (Hh*Ww)   // 9216
#define AH 11
#define Rr 512
#define CP (Cc/2)     // 256 dwords per point (bf16 NHWC)

__device__ __forceinline__ u16 f2bf(float f){
  u32 u = __float_as_uint(f);
  u += 0x7fffu + ((u>>16)&1u);
  return (u16)(u>>16);
}
__device__ __forceinline__ u32 pk2(float a, float b){
  return (u32)f2bf(a) | ((u32)f2bf(b)<<16);
}

// ---- fp32 NCHW -> bf16-pair (u32) NHWC transpose; 128hw x 128c tile ----
// Phase-2 vectorized: lane owns a swizzled quad -> ds_read_b128 + uniform
// 4-way permute + global_store_dwordx4 (4x fewer epilogue instructions).
// Block (0,0,0) additionally performs the roi batch counting-sort (folded
// kernel: saves one launch; hidden under the other 1151 blocks).
__global__ __launch_bounds__(256)
void transpose_kernel(const float* __restrict__ in, u32* __restrict__ out,
                      const float* __restrict__ rois, int* __restrict__ idx){
  __shared__ u32 tile[128*64];   // 32 KB
  const int t = threadIdx.x;
  const int hw0 = blockIdx.x*128, c0 = blockIdx.y*128, b = blockIdx.z;
  {
    const int q = t & 31, cp0 = t >> 5;           // q: hw quad, cp0: 0..7
    const float* ib = in + ((size_t)(b*Cc + c0))*HWc + hw0 + 4*q;
    #pragma unroll
    for (int p=0;p<8;++p){
      const int cp = cp0 + p*8;                   // 0..63 channel pair in tile
      const float* pa = ib + (size_t)(2*cp)*HWc;
      float4 A = *(const float4*)pa;
      float4 B = *(const float4*)(pa + HWc);
      const int cs = cp ^ q;                      // (4q+i)>>2 == q for i<4
      tile[(4*q+0)*64 + cs] = pk2(A.x,B.x);
      tile[(4*q+1)*64 + cs] = pk2(A.y,B.y);
      tile[(4*q+2)*64 + cs] = pk2(A.z,B.z);
      tile[(4*q+3)*64 + cs] = pk2(A.w,B.w);
    }
  }
  __syncthreads();
  {
    const int l = t & 63, wv = t >> 6;
    const int rsub = l >> 4, q = l & 15;          // row-sub 0..3, quad 0..15
    u32* ob = out + ((size_t)b*HWc + hw0)*CP + (c0>>1);
    #pragma unroll
    for (int k=0;k<8;++k){
      const int hw = wv*32 + k*4 + rsub;
      const int s  = hw >> 2;                     // == 8*wv + k (uniform/wave)
      const int m  = s & 3;
      const u32* tp = &tile[hw*64 + ((4*q) ^ (s & ~3))];   // 16B aligned
      uint4 R = *(const uint4*)tp;                // R[j] = tile[base+j]
      uint4 W;                                    // W[i] = R[i^m]
      if      (m==0) W = R;
      else if (m==1) W = make_uint4(R.y,R.x,R.w,R.z);
      else if (m==2) W = make_uint4(R.z,R.w,R.x,R.y);
      else           W = make_uint4(R.w,R.z,R.y,R.x);
      *(uint4*)(ob + (size_t)hw*CP + 4*q) = W;
    }
  }
  // folded roi counting-sort: idx[0..3]=cnt, [4..7]=off, [8..519]=ids by batch
  if (idx && blockIdx.x==0 && blockIdx.y==0 && blockIdx.z==0){
    __shared__ int cnt[4], off[4], cur[4];
    if (t < 4) cnt[t] = 0;
    __syncthreads();
    int b0 = min(max((int)rois[t*5], 0), Bn-1);
    int b1 = min(max((int)rois[(t+256)*5], 0), Bn-1);
    atomicAdd(&cnt[b0], 1);
    atomicAdd(&cnt[b1], 1);
    __syncthreads();
    if (t == 0){
      int o = 0;
      for (int i=0;i<4;++i){ off[i]=o; cur[i]=o; o+=cnt[i]; }
    }
    __syncthreads();
    int p0 = atomicAdd(&cur[b0], 1); idx[8+p0] = t;
    int p1 = atomicAdd(&cur[b1], 1); idx[8+p1] = t+256;
    if (t < 4){ idx[t] = cnt[t]; idx[4+t] = off[t]; }
  }
}

// per-bin bilinear combine, exact fp op order of the reference path
__device__ __forceinline__ float2 bilin(const u32 v[16], const float cw[4], const float rw[4]){
  float ax=0.0f, ay=0.0f;
  #pragma unroll
  for (int i=0;i<4;++i){
    float cx=0.0f, cy=0.0f;
    #pragma unroll
    for (int j=0;j<4;++j){
      u32 d = v[i*4+j];
      cx = fmaf(cw[j], __uint_as_float(d<<16),           cx);
      cy = fmaf(cw[j], __uint_as_float(d & 0xffff0000u), cy);
    }
    ax = fmaf(rw[i], cx, ax);
    ay = fmaf(rw[i], cy, ay);
  }
  return make_float2(ax, ay);
}

// ---- fused RoIAlignAda + 3x3/s2 maxpool, NHWC bf16, channel-split 2 ----
// R7 = R6 XCD-pinned mapping (FETCH 131->26 MB, keep) + depth-4 pw pipeline.
//   bid = 8j + k, k = XCD (%8 round-robin). XCD k: batch k>>1, half k&1;
//   one (image, half) = 4.7 MB ~ one XCD L2 -> cross-iteration L2 residency.
__global__ __launch_bounds__(128)
void roi_align_max_nhwc(const u32* __restrict__ feat,
                        const float* __restrict__ rois,
                        float* __restrict__ out,
                        const int* __restrict__ idx)
{
  __shared__ __align__(16) int4   s_ro[AH];
  __shared__ __align__(16) float4 s_rw[AH];
  __shared__ __align__(16) int4   s_co[AH];
  __shared__ __align__(16) float4 s_cw[AH];
  __shared__ int s_b;
  __shared__ __align__(16) float s_out[256*25];   // 25.6 KB

  const int t   = threadIdx.x;
  const int bid = blockIdx.x;

  int r, half;
  if (idx){
    const int k = bid & 7;          // XCD under %8 round-robin
    const int j = bid >> 3;         // 0..127 slot within XCD
    const int b = k >> 1;
    half = k & 1;
    const int cntb = idx[b];
    if (j < cntb && j < 128){
      r = idx[8 + idx[4+b] + j];    // native: j-th roi of this XCD's batch
    } else {
      // deficit slot: pull from the global leftover pool (bijective rank)
      int dr = 0;
      for (int b2=0; b2<b; ++b2) dr += max(0, 128 - idx[b2]);
      dr += j - min(cntb, 128);
      int acc = 0; r = 0;
      for (int b2=0; b2<4; ++b2){
        int ex = max(0, idx[b2] - 128);
        if (dr < acc + ex){ r = idx[8 + idx[4+b2] + 128 + (dr - acc)]; break; }
        acc += ex;
      }
    }
  } else {
    r = bid >> 1; half = bid & 1;
  }

  if (t == 0){
    int b = (int)rois[r*5+0];
    s_b = min(max(b, 0), Bn-1);
  }

  // geometry: threads 0..10 -> rows (ph), threads 64..74 -> cols (pw)
  if (t < AH || (t >= 64 && t < 64+AH)){
    const bool isrow = (t < AH);
    const int  p = isrow ? t : t-64;
    const float* rp = rois + r*5;
    const float c1 = rp[isrow?2:1], c2 = rp[isrow?4:3];
    // replicate np float32 ops exactly (no fp contraction at validity boundaries)
    float lo  = __fmul_rn(c1, 0.125f);
    float hi  = __fmul_rn(c2, 0.125f);
    float ext = fmaxf(__fsub_rn(hi,lo), 0.0f);
    float bin = __fdiv_rn(ext, 10.0f);
    float ctr = __fadd_rn(lo, __fmul_rn((float)p, bin));
    float strd = fmaxf(1.0f, rintf(__fdiv_rn(bin, 3.0f)));   // half-even == jnp.round
    bool ok = (ctr >= 0.0f) && (ctr < 96.0f);
    int rws[6]; float wts[6]; int nv=0;
    #pragma unroll
    for (int s=0;s<3;++s){
      float cc = __fadd_rn(ctr, __fmul_rn((float)(s-1), strd));
      bool vv = (cc >= 0.0f) && (cc < 96.0f);
      float fl = fminf(fmaxf(floorf(cc),0.0f),94.0f);
      float fr = __fsub_rn(cc, fl);
      int ri = (int)fl;
      rws[2*s]=ri; rws[2*s+1]=ri+1;
      wts[2*s]  = vv ? __fsub_rn(1.0f,fr) : 0.0f;
      wts[2*s+1]= vv ? fr : 0.0f;
      nv += vv?1:0;
    }
    float sc = ok ? (1.0f/(float)nv) : 0.0f;   // folds center_ok + 1/cnt (separable)
    // dedupe-merge (stride==1 here => <=4 unique), pad to 4 with w=0
    int cr[4]={0,0,0,0}; float cwv[4]={0.0f,0.0f,0.0f,0.0f}; int n=0;
    for (int k=0;k<6;++k){
      float wk=wts[k]; if (wk==0.0f) continue;
      int rr=rws[k]; bool fnd=false;
      for (int j=0;j<n;++j) if (cr[j]==rr){ cwv[j]+=wk; fnd=true; break; }
      if (!fnd && n<4){ cr[n]=rr; cwv[n]=wk; ++n; }
    }
    const int mul = isrow ? (Ww*CP*4) : (CP*4);   // BYTE offsets
    if (isrow){
      s_ro[p] = make_int4(cr[0]*mul, cr[1]*mul, cr[2]*mul, cr[3]*mul);
      s_rw[p] = make_float4(cwv[0]*sc, cwv[1]*sc, cwv[2]*sc, cwv[3]*sc);
    } else {
      s_co[p] = make_int4(cr[0]*mul, cr[1]*mul, cr[2]*mul, cr[3]*mul);
      s_cw[p] = make_float4(cwv[0]*sc, cwv[1]*sc, cwv[2]*sc, cwv[3]*sc);
    }
  }
  __syncthreads();

  const char* fb = (const char*)(feat + (size_t)s_b*((size_t)HWc*CP));
  const int tb4 = (half*128 + t)*4;            // byte offset of this thread's dword

  // hoist column byte-voffsets + weights into registers (R0-proven pattern)
  int   vo[AH][4]; float cwr[AH][4];
  #pragma unroll
  for (int pw=0; pw<AH; ++pw){
    int4 c4 = s_co[pw]; float4 w4 = s_cw[pw];
    vo[pw][0]=tb4+c4.x; vo[pw][1]=tb4+c4.y; vo[pw][2]=tb4+c4.z; vo[pw][3]=tb4+c4.w;
    cwr[pw][0]=w4.x; cwr[pw][1]=w4.y; cwr[pw][2]=w4.z; cwr[pw][3]=w4.w;
  }

  float2 awin[5];
  #pragma unroll 1
  for (int ph=0; ph<AH; ++ph){
    int4   r4 = s_ro[ph];
    float4 w4 = s_rw[ph];
    // scalar row bases (SGPR-pair addressing for the gathers)
    const char* r0 = fb + __builtin_amdgcn_readfirstlane(r4.x);
    const char* r1 = fb + __builtin_amdgcn_readfirstlane(r4.y);
    const char* r2 = fb + __builtin_amdgcn_readfirstlane(r4.z);
    const char* r3 = fb + __builtin_amdgcn_readfirstlane(r4.w);
    const float rw_[4] = {w4.x, w4.y, w4.z, w4.w};
    float2 binr[AH];
    u32 va[16], vb[16], vc[16], vd[16];

#define LDV(dst, PW) do{                              \
    dst[ 0] = *(const u32*)(r0 + vo[PW][0]);          \
    dst[ 1] = *(const u32*)(r0 + vo[PW][1]);          \
    dst[ 2] = *(const u32*)(r0 + vo[PW][2]);          \
    dst[ 3] = *(const u32*)(r0 + vo[PW][3]);          \
    dst[ 4] = *(const u32*)(r1 + vo[PW][0]);          \
    dst[ 5] = *(const u32*)(r1 + vo[PW][1]);          \
    dst[ 6] = *(const u32*)(r1 + vo[PW][2]);          \
    dst[ 7] = *(const u32*)(r1 + vo[PW][3]);          \
    dst[ 8] = *(const u32*)(r2 + vo[PW][0]);          \
    dst[ 9] = *(const u32*)(r2 + vo[PW][1]);          \
    dst[10] = *(const u32*)(r2 + vo[PW][2]);          \
    dst[11] = *(const u32*)(r2 + vo[PW][3]);          \
    dst[12] = *(const u32*)(r3 + vo[PW][0]);          \
    dst[13] = *(const u32*)(r3 + vo[PW][1]);          \
    dst[14] = *(const u32*)(r3 + vo[PW][2]);          \
    dst[15] = *(const u32*)(r3 + vo[PW][3]);          \
  }while(0)
#define CMP(src, PW) binr[PW] = bilin(src, cwr[PW], rw_)

    // 4-deep pipeline: math for bin pw overlaps 48+ in-flight gathers
    LDV(va, 0); LDV(vb, 1); LDV(vc, 2); LDV(vd, 3);
    CMP(va, 0); LDV(va, 4);
    CMP(vb, 1); LDV(vb, 5);
    CMP(vc, 2); LDV(vc, 6);
    CMP(vd, 3); LDV(vd, 7);
    CMP(va, 4); LDV(va, 8);
    CMP(vb, 5); LDV(vb, 9);
    CMP(vc, 6); LDV(vc, 10);
    CMP(vd, 7);
    CMP(va, 8);
    CMP(vb, 9);
    CMP(vc, 10);
#undef LDV
#undef CMP

    float2 rm[5];
    #pragma unroll
    for (int ox=0; ox<5; ++ox){
      rm[ox].x = fmaxf(fmaxf(binr[2*ox].x, binr[2*ox+1].x), binr[2*ox+2].x);
      rm[ox].y = fmaxf(fmaxf(binr[2*ox].y, binr[2*ox+1].y), binr[2*ox+2].y);
    }
    if (ph == 0){
      #pragma unroll
      for (int ox=0; ox<5; ++ox) awin[ox] = rm[ox];
    } else if (ph & 1){
      #pragma unroll
      for (int ox=0; ox<5; ++ox){
        awin[ox].x = fmaxf(awin[ox].x, rm[ox].x);
        awin[ox].y = fmaxf(awin[ox].y, rm[ox].y);
      }
    } else {
      const int oy = (ph-2) >> 1;
      #pragma unroll
      for (int ox=0; ox<5; ++ox){
        s_out[(2*t  )*25 + oy*5 + ox] = fmaxf(awin[ox].x, rm[ox].x);
        s_out[(2*t+1)*25 + oy*5 + ox] = fmaxf(awin[ox].y, rm[ox].y);
        awin[ox] = rm[ox];
      }
    }
  }
  __syncthreads();

  // coalesced float4 store of this half's [256][5][5] chunk
  float4* dst = (float4*)(out + (size_t)r*(Cc*25) + half*(256*25));
  const float4* src = (const float4*)s_out;
  for (int k=t; k<(256*25)/4; k+=128) dst[k]=src[k];
}

// ---- fallback: NCHW fp32 direct (known-correct, used only if ws too small) ----
__global__ __launch_bounds__(512, 1)
void roi_align_max_nchw(const float* __restrict__ feat,
                        const float* __restrict__ rois,
                        float* __restrict__ out)
{
  __shared__ int   s_roff[AH][6];
  __shared__ float s_rw  [AH][6];
  __shared__ int   s_coff[AH][6];
  __shared__ float s_cw  [AH][6];
  __shared__ int   s_b;
  __shared__ __align__(16) float s_out[Cc*25];

  const int t = threadIdx.x;
  const int r = blockIdx.x;

  if (t < AH*6){
    ((float*)s_rw)[t] = 0.0f;  ((int*)s_roff)[t] = 0;
    ((float*)s_cw)[t] = 0.0f;  ((int*)s_coff)[t] = 0;
  }
  if (t == 0){
    int b = (int)rois[r*5+0];
    s_b = min(max(b, 0), Bn-1);
  }
  __syncthreads();

  if (t < AH || (t >= 64 && t < 64+AH)){
    const bool isrow = (t < AH);
    const int  p = isrow ? t : t-64;
    const float* rp = rois + r*5;
    const float c1 = rp[isrow?2:1], c2 = rp[isrow?4:3];
    float lo  = __fmul_rn(c1, 0.125f);
    float hi  = __fmul_rn(c2, 0.125f);
    float ext = fmaxf(__fsub_rn(hi,lo), 0.0f);
    float bin = __fdiv_rn(ext, 10.0f);
    float ctr = __fadd_rn(lo, __fmul_rn((float)p, bin));
    float strd = fmaxf(1.0f, rintf(__fdiv_rn(bin, 3.0f)));
    bool ok = (ctr >= 0.0f) && (ctr < 96.0f);
    int rws[6]; float wts[6]; int nv=0;
    #pragma unroll
    for (int s=0;s<3;++s){
      float cc = __fadd_rn(ctr, __fmul_rn((float)(s-1), strd));
      bool vv = (cc >= 0.0f) && (cc < 96.0f);
      float fl = fminf(fmaxf(floorf(cc),0.0f),94.0f);
      float fr = __fsub_rn(cc, fl);
      int ri = (int)fl;
      rws[2*s]=ri; rws[2*s+1]=ri+1;
      wts[2*s]  = vv ? __fsub_rn(1.0f,fr) : 0.0f;
      wts[2*s+1]= vv ? fr : 0.0f;
      nv += vv?1:0;
    }
    float sc = ok ? (1.0f/(float)nv) : 0.0f;
    int cr[6]; float cw[6]; int n=0;
    for (int k=0;k<6;++k){
      float wk=wts[k]; if (wk==0.0f) continue;
      if (n>0 && cr[n-1]==rws[k]) cw[n-1]+=wk;
      else { cr[n]=rws[k]; cw[n]=wk; ++n; }
    }
    const int mul = isrow ? Ww : 1;
    for (int k=0;k<n;++k){
      int off = cr[k]*mul;
      float wv = cw[k]*sc;
      if (isrow){ s_roff[p][k]=off; s_rw[p][k]=wv; }
      else      { s_coff[p][k]=off; s_cw[p][k]=wv; }
    }
  }
  __syncthreads();

  const float* f0 = feat + ((size_t)s_b*Cc + t)*HWc;
  float awin[5];
  for (int ph=0; ph<AH; ++ph){
    float binrow[AH];
    #pragma unroll
    for (int pw=0; pw<AH; ++pw){
      float acc = 0.0f;
      #pragma unroll
      for (int ai=0; ai<6; ++ai){
        float ra = s_rw[ph][ai];
        if (ra == 0.0f) continue;
        int ro = s_roff[ph][ai];
        #pragma unroll
        for (int bi=0; bi<6; ++bi){
          float cb = s_cw[pw][bi];
          if (cb == 0.0f) continue;
          acc = fmaf(ra*cb, f0[ro + s_coff[pw][bi]], acc);
        }
      }
      binrow[pw] = acc;
    }
    float rm[5];
    #pragma unroll
    for (int ox=0; ox<5; ++ox)
      rm[ox] = fmaxf(fmaxf(binrow[2*ox], binrow[2*ox+1]), binrow[2*ox+2]);
    if (ph == 0){
      #pragma unroll
      for (int ox=0; ox<5; ++ox) awin[ox] = rm[ox];
    } else if (ph & 1){
      #pragma unroll
      for (int ox=0; ox<5; ++ox) awin[ox] = fmaxf(awin[ox], rm[ox]);
    } else {
      int oy = (ph-2) >> 1;
      #pragma unroll
      for (int ox=0; ox<5; ++ox){
        s_out[t*25 + oy*5 + ox] = fmaxf(awin[ox], rm[ox]);
        awin[ox] = rm[ox];
      }
    }
  }
  __syncthreads();

  float4* dst = (float4*)(out + (size_t)r*(Cc*25));
  const float4* src = (const float4*)s_out;
  for (int k=t; k<(Cc*25)/4; k+=512) dst[k]=src[k];
}

extern "C" void kernel_launch(void* const* d_in, const int* in_sizes, int n_in,
                              void* d_out, int out_size, void* d_ws, size_t ws_size,
                              hipStream_t stream)
{
  (void)in_sizes; (void)n_in; (void)out_size;
  const float* feat = (const float*)d_in[0];
  const float* rois = (const float*)d_in[1];
  float* out = (float*)d_out;
  const size_t need = (size_t)Bn*HWc*Cc*sizeof(u16);   // 37.75 MB bf16 NHWC
  if (ws_size >= need){
    u32* ws = (u32*)d_ws;
    int* idx = nullptr;
    if (ws_size >= need + 4096) idx = (int*)((char*)d_ws + need);
    dim3 g(HWc/128, Cc/128, Bn);
    transpose_kernel<<<g, 256, 0, stream>>>(feat, ws, rois, idx);
    roi_align_max_nhwc<<<Rr*2, 128, 0, stream>>>(ws, rois, out, idx);
  } else {
    roi_align_max_nchw<<<Rr, 512, 0, stream>>>(feat, rois, out);
  }
}